// Round 7
// baseline (879.744 us; speedup 1.0000x reference)
//
#include <hip/hip_runtime.h>
#include <hip/hip_fp16.h>

#define N_NODES 50000
#define N_EDGES 1600000
#define T_STEPS 50
#define DT      0.02f
#define NB      256    // buckets == step blocks (1 per CU)
#define NPB     196    // nodes per bucket
#define CAP     6912   // max edges per bucket (mean 6250, +8 sigma)
#define TILE    4096   // edges per bucket_kernel block
#define NCH     8      // source chunks
#define CHUNK   6250   // nodes per chunk (NCH*CHUNK == N_NODES)
#define SREG    7      // ceil(CHUNK/1024) staging registers

// ---------------- setup ----------------

__global__ __launch_bounds__(256) void zero_kernel(int* __restrict__ bucket_count) {
    bucket_count[threadIdx.x] = 0;
}

// ---------------- bucketing: staged, line-friendly appends ----------------
// u64 item: low 32 = record (src | fp16w<<16), high 32 = target-within-bucket
__global__ __launch_bounds__(256) void bucket_kernel(
    const int* __restrict__ src, const int* __restrict__ tgt,
    const float* __restrict__ sign, const float* __restrict__ syn_count,
    const float* __restrict__ syn_strength,
    int* __restrict__ bucket_count, unsigned long long* __restrict__ rec_buf)
{
    __shared__ int hist[NB], base_s[NB], cur[NB];
    int tid = threadIdx.x;
    hist[tid] = 0;
    __syncthreads();

    int e0 = blockIdx.x * TILE + tid;
    int bkt[16];
    unsigned long long item[16];
#pragma unroll
    for (int k = 0; k < 16; ++k) {
        int e = e0 + k * 256;
        if (e < N_EDGES) {
            int t = tgt[e];
            int b = t / NPB;
            int tl = t - b * NPB;
            float w = sign[e] * fmaxf(syn_count[e], 0.f) * fmaxf(syn_strength[e], 0.f);
            unsigned int rec = (unsigned int)src[e] |
                               ((unsigned int)__half_as_ushort(__float2half(w)) << 16);
            bkt[k] = b;
            item[k] = (unsigned long long)rec | ((unsigned long long)tl << 32);
            atomicAdd(&hist[b], 1);
        } else {
            bkt[k] = -1;
        }
    }
    __syncthreads();
    base_s[tid] = atomicAdd(&bucket_count[tid], hist[tid]);
    cur[tid] = 0;
    __syncthreads();
#pragma unroll
    for (int k = 0; k < 16; ++k) {
        if (bkt[k] >= 0) {
            int p = base_s[bkt[k]] + atomicAdd(&cur[bkt[k]], 1);
            if (p < CAP) rec_buf[(size_t)bkt[k] * CAP + p] = item[k];
        }
    }
}

// ---------------- per-bucket counting sort by (target, src-chunk) ----------------
// Emits bucket-contiguous CSR (edges_g) + per-(node,chunk) offsets co[n*9+c]
// (c=0..7 begins, c=8 end), plus folded node init (ab, v, rates0).
__global__ __launch_bounds__(256) void sort_kernel(
    const int* __restrict__ bucket_count,
    const unsigned long long* __restrict__ rec_buf,
    const float* __restrict__ bias, const float* __restrict__ time_const,
    unsigned int* __restrict__ edges_g, int* __restrict__ co,
    float2* __restrict__ ab, float* __restrict__ v /* [4][N] SoA */,
    uint2* __restrict__ rates0 /* half4 per node */)
{
    __shared__ unsigned int sorted[CAP];           // 27.6 KB
    __shared__ int kcnt[NPB * NCH];                // 6.3 KB
    __shared__ int kcur[NPB * NCH];                // 6.3 KB
    __shared__ int nsum[256];

    int b = blockIdx.x, tid = threadIdx.x;
    int node_base = b * NPB;
    int n_nodes = min(NPB, N_NODES - node_base);
    int ebase = b * CAP;
    int cnt = min(bucket_count[b], CAP);

    for (int i = tid; i < NPB * NCH; i += 256) kcnt[i] = 0;
    __syncthreads();

    // pass 1: histogram by key = tl*NCH + chunk(src)
    for (int i = tid; i < cnt; i += 256) {
        unsigned long long it = rec_buf[(size_t)b * CAP + i];
        int tl = (int)(it >> 32);
        int c  = (int)((unsigned int)it & 0xFFFFu) / CHUNK;
        atomicAdd(&kcnt[tl * NCH + c], 1);
    }
    __syncthreads();

    // per-node totals, block scan (Hillis-Steele over 256)
    int my_tot = 0;
    if (tid < NPB) {
#pragma unroll
        for (int k = 0; k < NCH; ++k) my_tot += kcnt[tid * NCH + k];
    }
    nsum[tid] = my_tot;
    __syncthreads();
    for (int off = 1; off < 256; off <<= 1) {
        int val = (tid >= off) ? nsum[tid - off] : 0;
        __syncthreads();
        nsum[tid] += val;
        __syncthreads();
    }

    // per-key exclusive offsets + co writes + folded node init
    if (tid < n_nodes) {
        int run = (tid == 0) ? 0 : nsum[tid - 1];
        int gn = node_base + tid;
#pragma unroll
        for (int k = 0; k < NCH; ++k) {
            kcur[tid * NCH + k] = run;
            co[gn * (NCH + 1) + k] = ebase + run;
            run += kcnt[tid * NCH + k];
        }
        co[gn * (NCH + 1) + NCH] = ebase + run;

        float bb  = bias[gn];
        float tau = fmaxf(time_const[gn], DT);
        ab[gn] = make_float2(DT / tau, bb);
        v[gn] = bb; v[N_NODES + gn] = bb;
        v[2 * N_NODES + gn] = bb; v[3 * N_NODES + gn] = bb;
        __half hr = __float2half(fmaxf(bb, 0.f));
        __half2 h2 = __halves2half2(hr, hr);
        uint2 r0; r0.x = *(unsigned int*)&h2; r0.y = r0.x;
        rates0[gn] = r0;
    }
    __syncthreads();

    // pass 2: place
    for (int i = tid; i < cnt; i += 256) {
        unsigned long long it = rec_buf[(size_t)b * CAP + i];
        int tl = (int)(it >> 32);
        int c  = (int)((unsigned int)it & 0xFFFFu) / CHUNK;
        int p = atomicAdd(&kcur[tl * NCH + c], 1);
        sorted[p] = (unsigned int)it;
    }
    __syncthreads();

    // coalesced CSR write
    for (int i = tid; i < cnt; i += 256) edges_g[ebase + i] = sorted[i];
}

// ---------------- per-step: LDS-staged gather + Euler update ----------------
__device__ __forceinline__ float rec_w(unsigned int rec) {
    return __half2float(__ushort_as_half((unsigned short)(rec >> 16)));
}
__device__ __forceinline__ float4 h4_to_f4(uint2 g) {
    __half2 h01 = *(__half2*)&g.x;
    __half2 h23 = *(__half2*)&g.y;
    float2 f01 = __half22float2(h01);
    float2 f23 = __half22float2(h23);
    return make_float4(f01.x, f01.y, f23.x, f23.y);
}

__global__ __launch_bounds__(1024) void step_kernel(
    const uint2* __restrict__ rates_in /* half4/node */,
    __half* __restrict__ rates_out /* 4 halves/node */,
    float* __restrict__ v /* [4][N] SoA */,
    const float2* __restrict__ ab,
    const int* __restrict__ co, const unsigned int* __restrict__ edges,
    const float* __restrict__ x, float* __restrict__ out, int t)
{
    __shared__ uint2 lds_r[CHUNK];   // 50 KB

    int b = blockIdx.x, tid = threadIdx.x;
    int node_base = b * NPB;
    int n_nodes = min(NPB, N_NODES - node_base);
    int group = tid >> 2, lane = tid & 3;
    bool active = group < n_nodes;
    int gn = node_base + group;
    float4 acc = make_float4(0.f, 0.f, 0.f, 0.f);

    // per-node chunk offsets loaded once (co stride 9)
    int off9[NCH + 1];
    if (active) {
#pragma unroll
        for (int k = 0; k <= NCH; ++k) off9[k] = co[gn * (NCH + 1) + k];
    } else {
#pragma unroll
        for (int k = 0; k <= NCH; ++k) off9[k] = 0;
    }

    // preload chunk 0 into registers
    uint2 st[SREG];
#pragma unroll
    for (int k = 0; k < SREG; ++k) {
        int i = tid + k * 1024;
        st[k] = (i < CHUNK) ? rates_in[i] : make_uint2(0u, 0u);
    }

    for (int c = 0; c < NCH; ++c) {
        __syncthreads();             // previous phase's LDS reads done
#pragma unroll
        for (int k = 0; k < SREG; ++k) {
            int i = tid + k * 1024;
            if (i < CHUNK) lds_r[i] = st[k];
        }
        if (c + 1 < NCH) {           // prefetch next chunk (overlaps this phase)
            const uint2* nxt = rates_in + (c + 1) * CHUNK;
#pragma unroll
            for (int k = 0; k < SREG; ++k) {
                int i = tid + k * 1024;
                st[k] = (i < CHUNK) ? nxt[i] : make_uint2(0u, 0u);
            }
        }
        __syncthreads();             // staged chunk visible

        int beg = off9[c], end = off9[c + 1];
        int cb = c * CHUNK;
        int i = beg + lane;
        // fast path: 2 predicated records (mean sublist len 4 on 4 lanes)
        unsigned int r0 = (i     < end) ? edges[i]     : (unsigned int)cb;
        unsigned int r1 = (i + 4 < end) ? edges[i + 4] : (unsigned int)cb;
        float4 a0 = h4_to_f4(lds_r[(int)(r0 & 0xFFFFu) - cb]);
        float4 a1 = h4_to_f4(lds_r[(int)(r1 & 0xFFFFu) - cb]);
        float w0 = rec_w(r0), w1 = rec_w(r1);
        acc.x = fmaf(a0.x, w0, acc.x); acc.y = fmaf(a0.y, w0, acc.y);
        acc.z = fmaf(a0.z, w0, acc.z); acc.w = fmaf(a0.w, w0, acc.w);
        acc.x = fmaf(a1.x, w1, acc.x); acc.y = fmaf(a1.y, w1, acc.y);
        acc.z = fmaf(a1.z, w1, acc.z); acc.w = fmaf(a1.w, w1, acc.w);
        // rare tail (P ~ 2%)
        for (i += 8; i < end; i += 4) {
            unsigned int rr = edges[i];
            float ww = rec_w(rr);
            float4 ar = h4_to_f4(lds_r[(int)(rr & 0xFFFFu) - cb]);
            acc.x = fmaf(ar.x, ww, acc.x); acc.y = fmaf(ar.y, ww, acc.y);
            acc.z = fmaf(ar.z, ww, acc.z); acc.w = fmaf(ar.w, ww, acc.w);
        }
    }

    // reduce across the 4 lanes of the group
    acc.x += __shfl_xor(acc.x, 1, 64); acc.y += __shfl_xor(acc.y, 1, 64);
    acc.z += __shfl_xor(acc.z, 1, 64); acc.w += __shfl_xor(acc.w, 1, 64);
    acc.x += __shfl_xor(acc.x, 2, 64); acc.y += __shfl_xor(acc.y, 2, 64);
    acc.z += __shfl_xor(acc.z, 2, 64); acc.w += __shfl_xor(acc.w, 2, 64);

    if (active) {   // lane l handles batch element l
        float sum = (lane == 0) ? acc.x : (lane == 1) ? acc.y
                  : (lane == 2) ? acc.z : acc.w;
        float2 abv = ab[gn];
        const int TN = T_STEPS * N_NODES;
        int vi = lane * N_NODES + gn;
        int oi = lane * TN + t * N_NODES + gn;
        float vv = v[vi];
        float vn = vv + abv.x * (abv.y + sum + x[oi] - vv);
        v[vi] = vn;
        float r = fmaxf(vn, 0.f);
        rates_out[gn * 4 + lane] = __float2half(r);
        out[oi] = r;
    }
}

// ---------------- launch ----------------

extern "C" void kernel_launch(void* const* d_in, const int* in_sizes, int n_in,
                              void* d_out, int out_size, void* d_ws, size_t ws_size,
                              hipStream_t stream) {
    const float* x            = (const float*)d_in[0];
    const float* bias         = (const float*)d_in[1];
    const float* time_const   = (const float*)d_in[2];
    const float* sign         = (const float*)d_in[3];
    const float* syn_count    = (const float*)d_in[4];
    const float* syn_strength = (const float*)d_in[5];
    const int*   src_idx      = (const int*)d_in[6];
    const int*   tgt_idx      = (const int*)d_in[7];
    float* out = (float*)d_out;

    char* ws = (char*)d_ws;
    size_t off = 0;
    auto alloc = [&](size_t bytes) -> void* {
        void* p = ws + off;
        off = (off + bytes + 255) & ~(size_t)255;
        return p;
    };
    float*  v       = (float*) alloc((size_t)N_NODES * 4 * 4);   // [4][N] SoA
    uint2*  rates_a = (uint2*) alloc((size_t)N_NODES * 8);       // half4 per node
    uint2*  rates_b = (uint2*) alloc((size_t)N_NODES * 8);
    float2* ab      = (float2*)alloc((size_t)N_NODES * 8);
    int*    co      = (int*)   alloc((size_t)N_NODES * (NCH + 1) * 4); // 1.8 MB
    int*    bucket_count = (int*)alloc((size_t)NB * 4);
    unsigned int* edges = (unsigned int*)alloc((size_t)NB * CAP * 4);  // 7.1 MB
    unsigned long long* rec_buf =
        (unsigned long long*)alloc((size_t)NB * CAP * 8);   // 14.2 MB

    int nb_tiles = (N_EDGES + TILE - 1) / TILE;

    zero_kernel<<<1, 256, 0, stream>>>(bucket_count);
    bucket_kernel<<<nb_tiles, 256, 0, stream>>>(src_idx, tgt_idx, sign, syn_count,
                                                syn_strength, bucket_count, rec_buf);
    sort_kernel<<<NB, 256, 0, stream>>>(bucket_count, rec_buf, bias, time_const,
                                        edges, co, ab, v, rates_a);

    for (int t = 0; t < T_STEPS; ++t) {
        const uint2* rin  = (t & 1) ? rates_b : rates_a;
        __half*      rout = (__half*)((t & 1) ? rates_a : rates_b);
        step_kernel<<<NB, 1024, 0, stream>>>(rin, rout, v, ab, co, edges,
                                             x, out, t);
    }
}